// Round 2
// baseline (649.365 us; speedup 1.0000x reference)
//
#include <hip/hip_runtime.h>

typedef __attribute__((ext_vector_type(8))) short short8;
typedef __attribute__((ext_vector_type(4))) float f32x4;
typedef unsigned short ushort_t;
typedef unsigned int u32;
typedef unsigned long long u64;

#define MFMA16(a,b,c) __builtin_amdgcn_mfma_f32_16x16x32_bf16((a),(b),(c),0,0,0)

__device__ __forceinline__ ushort_t f2bf(float f){
  union { float f; u32 u; } v; v.f = f;
  u32 r = v.u + 0x7fffu + ((v.u >> 16) & 1u);
  return (ushort_t)(r >> 16);
}
__device__ __forceinline__ float bf2f(ushort_t h){
  union { u32 u; float f; } v; v.u = ((u32)h) << 16; return v.f;
}

// DPP reductions (VALU-speed, no LDS/ds_swizzle traffic)
template<int CTRL>
__device__ __forceinline__ float dpp_add(float x){
  union { float f; int i; } a, b;
  a.f = x;
  b.i = __builtin_amdgcn_update_dpp(a.i, a.i, CTRL, 0xF, 0xF, false);
  return x + b.f;
}
template<int CTRL>
__device__ __forceinline__ float dpp_max(float x){
  union { float f; int i; } a, b;
  a.f = x;
  b.i = __builtin_amdgcn_update_dpp(a.i, a.i, CTRL, 0xF, 0xF, false);
  return fmaxf(x, b.f);
}
// full 16-lane (DPP row) reduce: xor1(quad_perm), xor2(quad_perm), half_mirror, mirror
__device__ __forceinline__ float red16_add(float x){
  x = dpp_add<0xB1>(x); x = dpp_add<0x4E>(x); x = dpp_add<0x141>(x); x = dpp_add<0x140>(x);
  return x;
}
__device__ __forceinline__ float red16_max(float x){
  x = dpp_max<0xB1>(x); x = dpp_max<0x4E>(x); x = dpp_max<0x141>(x); x = dpp_max<0x140>(x);
  return x;
}
// 8-lane (half-row) reduce
__device__ __forceinline__ float red8_add(float x){
  x = dpp_add<0xB1>(x); x = dpp_add<0x4E>(x); x = dpp_add<0x141>(x);
  return x;
}

// B=4096 T=32 C=180 H=6 HD=30 ; tokens = 131072
// ws layout (ushort elems): wqkv[6][3][32][192] | w1t[768][192] | w2t[192][768]
#define WQKV_ELEMS (576*192)
#define W1T_ELEMS  (768*192)
#define W2T_ELEMS  (192*768)

__global__ void prep_weights(const float* __restrict__ wq, const float* __restrict__ wk,
                             const float* __restrict__ wv, const float* __restrict__ w1,
                             const float* __restrict__ w2, ushort_t* __restrict__ ws){
  ushort_t* wqkv = ws;
  ushort_t* w1t = ws + WQKV_ELEMS;
  ushort_t* w2t = w1t + W1T_ELEMS;
  int tid = blockIdx.x * blockDim.x + threadIdx.x;
  int stride = gridDim.x * blockDim.x;
  for (int i = tid; i < WQKV_ELEMS; i += stride){
    int k = i % 192; int row = i / 192;
    int d = row & 31; int m = (row >> 5) % 3; int h = row / 96;
    float v = 0.f;
    if (d < 30 && k < 180){
      const float* W = (m == 0) ? wq : ((m == 1) ? wk : wv);
      v = W[(h*180 + k)*30 + d];
    }
    wqkv[i] = f2bf(v);
  }
  for (int i = tid; i < W1T_ELEMS; i += stride){
    int c = i % 192; int n = i / 192;
    float v = (n < 720 && c < 180) ? w1[c*720 + n] : 0.f;
    w1t[i] = f2bf(v);
  }
  for (int i = tid; i < W2T_ELEMS; i += stride){
    int c4 = i % 768; int n = i / 768;
    float v = (n < 180 && c4 < 720) ? w2[c4*180 + n] : 0.f;
    w2t[i] = f2bf(v);
  }
}

// ---------------- Kernel 1: LN1 + QKV + causal attention ; x2 = x + attn -> d_out
// 384 threads = 6 waves, 1 batch (32 tokens) per block, 1 head per wave.
#define HXS 200
#define ATS 196
__global__ __launch_bounds__(384, 3)
void attn_kernel(const float* __restrict__ x, const float* __restrict__ g1,
                 const float* __restrict__ be1, const ushort_t* __restrict__ wqkv,
                 float* __restrict__ xout){
  __shared__ ushort_t hx[32*HXS];      // bf16 x -> (in place) LN1 out; cols 180..191 zero
  __shared__ ushort_t att[32*ATS];     // attn out, [token][head*32+d]
  __shared__ ushort_t qp[6][32*40];    // per-wave: q rowmajor [t][d], then normalized P [t][s]
  __shared__ ushort_t kv[6][32*40];    // per-wave: k rowmajor [s][d], then vT [d][t]

  int tid = threadIdx.x;
  int wave = tid >> 6, lane = tid & 63;
  int quad = lane >> 4, c16 = lane & 15;
  long base = (long)blockIdx.x * 5760;   // batch * T * C floats

  // Phase A: coalesced float4 load x -> hx bf16 ; tail threads zero the k-pad
  #pragma unroll
  for (int it = 0; it < 4; it++){
    int idx = it*384 + tid;
    if (idx < 1440){
      f32x4 v = *(const f32x4*)(x + base + (long)idx*4);
      int row = (int)(((u32)idx * 745655u) >> 25);   // idx/45
      int col = idx - row*45;
      u32 p0 = (u32)f2bf(v.x) | ((u32)f2bf(v.y) << 16);
      u32 p1 = (u32)f2bf(v.z) | ((u32)f2bf(v.w) << 16);
      *(u64*)(hx + row*HXS + col*4) = (u64)p0 | ((u64)p1 << 32);
    } else {
      int p = idx - 1440;          // only it==3, p in [0,96)
      int row = (p*21846) >> 16;   // p/3
      int c = p - row*3;
      *(u64*)(hx + row*HXS + 180 + c*4) = 0ull;
    }
  }
  __syncthreads();

  // LN1 stats + in-place normalize (8 threads per row; rows wave-local)
  if (tid < 256){
    int row = tid >> 3, sub = tid & 7;
    int c0 = sub*23;
    float s1 = 0.f, s2 = 0.f;
    #pragma unroll
    for (int i = 0; i < 23; i++){
      int c = c0 + i;
      if (c < 180){ float v = bf2f(hx[row*HXS + c]); s1 += v; s2 += v*v; }
    }
    s1 = red8_add(s1); s2 = red8_add(s2);
    float mu = s1 * (1.f/180.f);
    float rstd = rsqrtf(s2 * (1.f/180.f) - mu*mu + 1e-5f);
    #pragma unroll
    for (int i = 0; i < 23; i++){
      int c = c0 + i;
      if (c < 180){
        float v = bf2f(hx[row*HXS + c]);
        hx[row*HXS + c] = f2bf((v - mu)*rstd*g1[c] + be1[c]);
      }
    }
  }
  __syncthreads();

  // ---- per-wave head: head = wave
  {
    const ushort_t* wbase = wqkv + wave*3*32*192;
    ushort_t* qs = qp[wave];
    ushort_t* ks = kv[wave];

    // QKV: M=32 tokens, N = [q0 q1 k0 k1 v0 v1], K=192
    f32x4 acc[2][6];
    #pragma unroll
    for (int i = 0; i < 2; i++)
      #pragma unroll
      for (int j = 0; j < 6; j++) acc[i][j] = (f32x4)0.f;
    #pragma unroll
    for (int kk = 0; kk < 6; kk++){
      int k0 = kk*32;
      short8 a[2];
      #pragma unroll
      for (int mt = 0; mt < 2; mt++)
        a[mt] = *(const short8*)(hx + (mt*16 + c16)*HXS + k0 + quad*8);
      short8 b[6];
      #pragma unroll
      for (int nb = 0; nb < 6; nb++)
        b[nb] = *(const short8*)(wbase + ((nb>>1)*32 + (nb&1)*16 + c16)*192 + k0 + quad*8);
      #pragma unroll
      for (int mt = 0; mt < 2; mt++)
        #pragma unroll
        for (int nb = 0; nb < 6; nb++)
          acc[mt][nb] = MFMA16(a[mt], b[nb], acc[mt][nb]);
    }
    // store q,k rowmajor (scalar u16)
    #pragma unroll
    for (int mt = 0; mt < 2; mt++)
      #pragma unroll
      for (int nt = 0; nt < 2; nt++)
        #pragma unroll
        for (int r = 0; r < 4; r++){
          int t = mt*16 + quad*4 + r;
          int d = nt*16 + c16;
          qs[t*40 + d] = f2bf(acc[mt][nt][r]);
          ks[t*40 + d] = f2bf(acc[mt][2+nt][r]);
        }
    // scores = q @ k^T
    f32x4 sacc[2][2];
    #pragma unroll
    for (int i = 0; i < 2; i++){ sacc[i][0] = (f32x4)0.f; sacc[i][1] = (f32x4)0.f; }
    short8 aq[2], bk[2];
    #pragma unroll
    for (int mt = 0; mt < 2; mt++) aq[mt] = *(const short8*)(qs + (mt*16 + c16)*40 + quad*8);
    #pragma unroll
    for (int nt = 0; nt < 2; nt++) bk[nt] = *(const short8*)(ks + (nt*16 + c16)*40 + quad*8);
    #pragma unroll
    for (int mt = 0; mt < 2; mt++)
      #pragma unroll
      for (int nt = 0; nt < 2; nt++)
        sacc[mt][nt] = MFMA16(aq[mt], bk[nt], sacc[mt][nt]);
    // softmax -> normalized P overwrites qs
    const float scl = 0.18257418583505537f;  // 30^-0.5
    #pragma unroll
    for (int mt = 0; mt < 2; mt++)
      #pragma unroll
      for (int r = 0; r < 4; r++){
        int t = mt*16 + quad*4 + r;
        float v0 = sacc[mt][0][r] * scl; if (c16 > t) v0 = -1e30f;
        float v1 = sacc[mt][1][r] * scl; if (16 + c16 > t) v1 = -1e30f;
        float m = red16_max(fmaxf(v0, v1));
        float e0 = __expf(v0 - m), e1 = __expf(v1 - m);
        float s = red16_add(e0 + e1);
        float inv = 1.f / s;
        qs[t*40 + c16]      = f2bf(e0 * inv);
        qs[t*40 + 16 + c16] = f2bf(e1 * inv);
      }
    // store vT over ks (b64); k frags already consumed (in-order LDS per wave)
    #pragma unroll
    for (int mt = 0; mt < 2; mt++)
      #pragma unroll
      for (int nt = 0; nt < 2; nt++){
        u32 p0 = (u32)f2bf(acc[mt][4+nt][0]) | ((u32)f2bf(acc[mt][4+nt][1]) << 16);
        u32 p1 = (u32)f2bf(acc[mt][4+nt][2]) | ((u32)f2bf(acc[mt][4+nt][3]) << 16);
        *(u64*)(ks + (nt*16 + c16)*40 + mt*16 + quad*4) = (u64)p0 | ((u64)p1 << 32);
      }
    // outT = vT @ P^T : M=d, N=token, K=s
    f32x4 oacc[2][2];
    #pragma unroll
    for (int i = 0; i < 2; i++){ oacc[i][0] = (f32x4)0.f; oacc[i][1] = (f32x4)0.f; }
    short8 av[2], bp[2];
    #pragma unroll
    for (int dt = 0; dt < 2; dt++) av[dt] = *(const short8*)(ks + (dt*16 + c16)*40 + quad*8);
    #pragma unroll
    for (int tt = 0; tt < 2; tt++) bp[tt] = *(const short8*)(qs + (tt*16 + c16)*40 + quad*8);
    #pragma unroll
    for (int dt = 0; dt < 2; dt++)
      #pragma unroll
      for (int tt = 0; tt < 2; tt++)
        oacc[dt][tt] = MFMA16(av[dt], bp[tt], oacc[dt][tt]);
    // write att[token][head*32+d] (b64 along d)
    #pragma unroll
    for (int dt = 0; dt < 2; dt++)
      #pragma unroll
      for (int tt = 0; tt < 2; tt++){
        u32 p0 = (u32)f2bf(oacc[dt][tt][0]) | ((u32)f2bf(oacc[dt][tt][1]) << 16);
        u32 p1 = (u32)f2bf(oacc[dt][tt][2]) | ((u32)f2bf(oacc[dt][tt][3]) << 16);
        *(u64*)(att + (tt*16 + c16)*ATS + wave*32 + dt*16 + quad*4) = (u64)p0 | ((u64)p1 << 32);
      }
  }
  __syncthreads();

  // Final: x2 = x (fp32 re-read, L2-hot) + attn ; coalesced float4 store
  #pragma unroll
  for (int it = 0; it < 4; it++){
    int idx = it*384 + tid;
    if (idx < 1440){
      f32x4 v = *(const f32x4*)(x + base + (long)idx*4);
      int row = (int)(((u32)idx * 745655u) >> 25);
      int col4 = (idx - row*45)*4;
      #pragma unroll
      for (int e = 0; e < 4; e++){
        int c = col4 + e;
        int h = (c*4370) >> 17;      // c/30
        int d = c - h*30;
        v[e] += bf2f(att[row*ATS + h*32 + d]);
      }
      *(f32x4*)(xout + base + (long)idx*4) = v;
    }
  }
}

// ---------------- Kernel 2: LN2 + MLP ; in-place residual update of d_out
// 256 threads = 4 waves, 32 tokens per block.
__global__ __launch_bounds__(256, 4)
void mlp_kernel(const float* __restrict__ g2, const float* __restrict__ be2,
                const float* __restrict__ b1, const float* __restrict__ b2,
                const ushort_t* __restrict__ w1t, const ushort_t* __restrict__ w2t,
                float* __restrict__ xio){
  __shared__ ushort_t h2[32*200];    // LN2 out bf16 (cols 180..191 zero)
  __shared__ ushort_t act[32*200];   // phase A: xb (bf16 x2) ; then relu chunk ; then mlp out
  int tid = threadIdx.x;
  int wave = tid >> 6, lane = tid & 63;
  int quad = lane >> 4, c16 = lane & 15;
  long base = (long)blockIdx.x * 5760;

  // Phase A: coalesced x2 load -> act (as xb)
  #pragma unroll
  for (int it = 0; it < 6; it++){
    int idx = it*256 + tid;
    if (idx < 1440){
      f32x4 v = *(const f32x4*)(xio + base + (long)idx*4);
      int row = (int)(((u32)idx * 745655u) >> 25);
      int col = idx - row*45;
      u32 p0 = (u32)f2bf(v.x) | ((u32)f2bf(v.y) << 16);
      u32 p1 = (u32)f2bf(v.z) | ((u32)f2bf(v.w) << 16);
      *(u64*)(act + row*200 + col*4) = (u64)p0 | ((u64)p1 << 32);
    }
  }
  __syncthreads();

  // LN2 stats from xb -> h2 (+ zero k-pad)
  {
    int row = tid >> 3, sub = tid & 7;
    int c0 = sub*23;
    float s1 = 0.f, s2 = 0.f;
    #pragma unroll
    for (int i = 0; i < 23; i++){
      int c = c0 + i;
      if (c < 180){ float v = bf2f(act[row*200 + c]); s1 += v; s2 += v*v; }
    }
    s1 = red8_add(s1); s2 = red8_add(s2);
    float mu = s1 * (1.f/180.f);
    float rstd = rsqrtf(s2 * (1.f/180.f) - mu*mu + 1e-5f);
    #pragma unroll
    for (int i = 0; i < 23; i++){
      int c = c0 + i;
      if (c < 180){
        float v = bf2f(act[row*200 + c]);
        h2[row*200 + c] = f2bf((v - mu)*rstd*g2[c] + be2[c]);
      }
    }
    if (sub < 6) ((u32*)h2)[row*100 + 90 + sub] = 0u;   // cols 180..191
  }
  __syncthreads();

  f32x4 outacc[2][3];
  #pragma unroll
  for (int i = 0; i < 2; i++)
    #pragma unroll
    for (int j = 0; j < 3; j++) outacc[i][j] = (f32x4)0.f;

  for (int ch = 0; ch < 4; ch++){
    // MLP1 transposed: actT = w1t_chunk @ h2^T ; A = w1t (global), B = h2 (LDS)
    f32x4 aacc[3][2];
    #pragma unroll
    for (int i = 0; i < 3; i++){ aacc[i][0] = (f32x4)0.f; aacc[i][1] = (f32x4)0.f; }
    #pragma unroll
    for (int kk = 0; kk < 6; kk++){
      int k0 = kk*32;
      short8 aw[3];
      #pragma unroll
      for (int mi = 0; mi < 3; mi++)
        aw[mi] = *(const short8*)(w1t + (size_t)(ch*192 + (wave*3+mi)*16 + c16)*192 + k0 + quad*8);
      short8 bh[2];
      #pragma unroll
      for (int tt = 0; tt < 2; tt++)
        bh[tt] = *(const short8*)(h2 + (tt*16 + c16)*200 + k0 + quad*8);
      #pragma unroll
      for (int mi = 0; mi < 3; mi++)
        #pragma unroll
        for (int tt = 0; tt < 2; tt++)
          aacc[mi][tt] = MFMA16(aw[mi], bh[tt], aacc[mi][tt]);
    }
    __syncthreads();   // prev chunk's MLP2 done reading act
    // bias + relu + pack to act rowmajor [token][n] (b64 along n)
    #pragma unroll
    for (int mi = 0; mi < 3; mi++){
      int nrel = (wave*3+mi)*16 + quad*4;
      int nabs = ch*192 + nrel;
      f32x4 bias = (f32x4)0.f;
      if (nabs < 720) bias = *(const f32x4*)(b1 + nabs);
      #pragma unroll
      for (int tt = 0; tt < 2; tt++){
        int token = tt*16 + c16;
        float v0 = fmaxf(aacc[mi][tt][0] + bias[0], 0.f);
        float v1 = fmaxf(aacc[mi][tt][1] + bias[1], 0.f);
        float v2 = fmaxf(aacc[mi][tt][2] + bias[2], 0.f);
        float v3 = fmaxf(aacc[mi][tt][3] + bias[3], 0.f);
        u32 p0 = (u32)f2bf(v0) | ((u32)f2bf(v1) << 16);
        u32 p1 = (u32)f2bf(v2) | ((u32)f2bf(v3) << 16);
        *(u64*)(act + token*200 + nrel) = (u64)p0 | ((u64)p1 << 32);
      }
    }
    __syncthreads();   // act ready
    // MLP2: out += act @ w2_chunk ; A = act (LDS), B = w2t (global)
    #pragma unroll
    for (int kk = 0; kk < 6; kk++){
      int k0 = kk*32;
      short8 aa[2];
      #pragma unroll
      for (int mt = 0; mt < 2; mt++)
        aa[mt] = *(const short8*)(act + (mt*16 + c16)*200 + k0 + quad*8);
      short8 bw[3];
      #pragma unroll
      for (int ntl = 0; ntl < 3; ntl++)
        bw[ntl] = *(const short8*)(w2t + (size_t)(wave*48 + ntl*16 + c16)*768 + ch*192 + k0 + quad*8);
      #pragma unroll
      for (int mt = 0; mt < 2; mt++)
        #pragma unroll
        for (int ntl = 0; ntl < 3; ntl++)
          outacc[mt][ntl] = MFMA16(aa[mt], bw[ntl], outacc[mt][ntl]);
    }
  }
  __syncthreads();   // last MLP2 done reading act
  // epilogue: mlp out (bf16) -> act [token][n]
  #pragma unroll
  for (int ntl = 0; ntl < 3; ntl++){
    int n = wave*48 + ntl*16 + c16;
    #pragma unroll
    for (int mt = 0; mt < 2; mt++)
      #pragma unroll
      for (int r = 0; r < 4; r++){
        int token = mt*16 + quad*4 + r;
        act[token*200 + n] = f2bf(outacc[mt][ntl][r]);
      }
  }
  __syncthreads();
  // Final: out = x2 (fp32 re-read, L2-hot) + mlp + b2 ; coalesced float4
  #pragma unroll
  for (int it = 0; it < 6; it++){
    int idx = it*256 + tid;
    if (idx < 1440){
      f32x4 v = *(const f32x4*)(xio + base + (long)idx*4);
      int row = (int)(((u32)idx * 745655u) >> 25);
      int col4 = (idx - row*45)*4;
      f32x4 bb = *(const f32x4*)(b2 + col4);
      u64 m = *(const u64*)(act + row*200 + col4);
      v.x += bf2f((ushort_t)(m      & 0xFFFF)) + bb.x;
      v.y += bf2f((ushort_t)((m>>16) & 0xFFFF)) + bb.y;
      v.z += bf2f((ushort_t)((m>>32) & 0xFFFF)) + bb.z;
      v.w += bf2f((ushort_t)((m>>48) & 0xFFFF)) + bb.w;
      *(f32x4*)(xio + base + (long)idx*4) = v;
    }
  }
}

extern "C" void kernel_launch(void* const* d_in, const int* in_sizes, int n_in,
                              void* d_out, int out_size, void* d_ws, size_t ws_size,
                              hipStream_t stream) {
  const float* x   = (const float*)d_in[0];
  const float* wq  = (const float*)d_in[1];
  const float* wk  = (const float*)d_in[2];
  const float* wv  = (const float*)d_in[3];
  const float* g1  = (const float*)d_in[4];
  const float* be1 = (const float*)d_in[5];
  const float* g2  = (const float*)d_in[6];
  const float* be2 = (const float*)d_in[7];
  const float* w1  = (const float*)d_in[8];
  const float* b1  = (const float*)d_in[9];
  const float* w2  = (const float*)d_in[10];
  const float* b2  = (const float*)d_in[11];
  ushort_t* ws   = (ushort_t*)d_ws;
  ushort_t* wqkv = ws;
  ushort_t* w1t  = ws + WQKV_ELEMS;
  ushort_t* w2t  = w1t + W1T_ELEMS;
  float* out = (float*)d_out;

  prep_weights<<<256, 256, 0, stream>>>(wq, wk, wv, w1, w2, ws);
  attn_kernel<<<4096, 384, 0, stream>>>(x, g1, be1, wqkv, out);
  mlp_kernel<<<4096, 256, 0, stream>>>(g2, be2, b1, b2, w1t, w2t, out);
}

// Round 3
// 492.446 us; speedup vs baseline: 1.3187x; 1.3187x over previous
//
#include <hip/hip_runtime.h>

typedef __attribute__((ext_vector_type(8))) short short8;
typedef __attribute__((ext_vector_type(4))) float f32x4;
typedef unsigned short ushort_t;
typedef unsigned int u32;
typedef unsigned long long u64;

#define MFMA16(a,b,c) __builtin_amdgcn_mfma_f32_16x16x32_bf16((a),(b),(c),0,0,0)

__device__ __forceinline__ ushort_t f2bf(float f){
  union { float f; u32 u; } v; v.f = f;
  u32 r = v.u + 0x7fffu + ((v.u >> 16) & 1u);
  return (ushort_t)(r >> 16);
}
__device__ __forceinline__ float bf2f(ushort_t h){
  union { u32 u; float f; } v; v.u = ((u32)h) << 16; return v.f;
}
__device__ __forceinline__ u64 pack4(float a, float b, float c, float d){
  u32 p0 = (u32)f2bf(a) | ((u32)f2bf(b) << 16);
  u32 p1 = (u32)f2bf(c) | ((u32)f2bf(d) << 16);
  return (u64)p0 | ((u64)p1 << 32);
}

template<int CTRL>
__device__ __forceinline__ float dpp_add(float x){
  union { float f; int i; } a, b;
  a.f = x;
  b.i = __builtin_amdgcn_update_dpp(a.i, a.i, CTRL, 0xF, 0xF, false);
  return x + b.f;
}
// 4-lane reduce (xor1, xor2 within quads)
__device__ __forceinline__ float red4_add(float x){
  x = dpp_add<0xB1>(x); x = dpp_add<0x4E>(x);
  return x;
}

// B=4096 T=32 C=180 H=6 HD=30 ; tokens=131072
// ws (ushort): wqkv[6][3][32][192] | w1t[768][192] | w2t[192][768]
#define WQKV_ELEMS (576*192)
#define W1T_ELEMS  (768*192)
#define W2T_ELEMS  (192*768)

#define S64 208   // stride (ushorts) for 64-row LDS bufs: 416B rows, 16B aligned
#define SSC 44    // stride for 32-row per-wave scratch: 88B rows, 8B aligned

__global__ void prep_weights(const float* __restrict__ wq, const float* __restrict__ wk,
                             const float* __restrict__ wv, const float* __restrict__ w1,
                             const float* __restrict__ w2, ushort_t* __restrict__ ws){
  ushort_t* wqkv = ws;
  ushort_t* w1t = ws + WQKV_ELEMS;
  ushort_t* w2t = w1t + W1T_ELEMS;
  int tid = blockIdx.x * blockDim.x + threadIdx.x;
  int stride = gridDim.x * blockDim.x;
  for (int i = tid; i < WQKV_ELEMS; i += stride){
    int k = i % 192; int row = i / 192;
    int d = row & 31; int m = (row >> 5) % 3; int h = row / 96;
    float v = 0.f;
    if (d < 30 && k < 180){
      const float* W = (m == 0) ? wq : ((m == 1) ? wk : wv);
      v = W[(h*180 + k)*30 + d];
    }
    wqkv[i] = f2bf(v);
  }
  for (int i = tid; i < W1T_ELEMS; i += stride){
    int c = i % 192; int n = i / 192;
    float v = (n < 720 && c < 180) ? w1[c*720 + n] : 0.f;
    w1t[i] = f2bf(v);
  }
  for (int i = tid; i < W2T_ELEMS; i += stride){
    int c4 = i % 768; int n = i / 768;
    float v = (n < 180 && c4 < 720) ? w2[c4*180 + n] : 0.f;
    w2t[i] = f2bf(v);
  }
}

union AttnU { ushort_t hx[64*S64]; ushort_t sc[4][2][32*SSC]; };

// ---------------- Kernel 1: LN1 + QKV + causal attention ; x2 = x+attn -> d_out
// 256 thr = 4 waves ; 64 tokens (2 batches)/block ; wave -> (batch, 3 heads)
__global__ __launch_bounds__(256, 2)
void attn_kernel(const float* __restrict__ x, const float* __restrict__ g1,
                 const float* __restrict__ be1, const ushort_t* __restrict__ wqkv,
                 float* __restrict__ xout){
  __shared__ AttnU u;                   // x bf16 (LN input) -> per-wave scratch
  __shared__ ushort_t hn[64*S64];       // LN1 out bf16 (cols 180..191 zero)
  __shared__ ushort_t att[64*S64];      // attn out [token][head*32+d]

  int tid = threadIdx.x;
  int wave = tid >> 6, lane = tid & 63;
  int quad = lane >> 4, c16 = lane & 15;
  long base = (long)blockIdx.x * 11520;   // 64 tokens * 180

  // Phase A: coalesced f32x4 x -> hx bf16 packed u64 ; zero pad cols 180..191
  #pragma unroll
  for (int it = 0; it < 12; it++){
    int idx = it*256 + tid;
    if (idx < 2880){
      f32x4 v = *(const f32x4*)(x + base + (long)idx*4);
      int row = (int)(((u32)idx * 745655u) >> 25);   // idx/45
      int col = idx - row*45;
      *(u64*)(u.hx + row*S64 + col*4) = pack4(v.x, v.y, v.z, v.w);
    } else {
      int p = idx - 2880;                 // [0,192)
      int row = (p*21846) >> 16;          // p/3
      int g = p - row*3;
      *(u64*)(u.hx + row*S64 + 180 + g*4) = 0ull;
    }
  }
  __syncthreads();

  // LN1: 4 threads/row, 48 cols each (pad zeros included; /180 fixed)
  {
    int row = tid >> 2, sub = tid & 3;
    int c0 = sub*48;
    float s1 = 0.f, s2 = 0.f;
    #pragma unroll
    for (int gi = 0; gi < 12; gi++){
      u64 m = *(const u64*)(u.hx + row*S64 + c0 + gi*4);
      #pragma unroll
      for (int e = 0; e < 4; e++){
        float v = bf2f((ushort_t)(m >> (16*e)));
        s1 += v; s2 += v*v;
      }
    }
    s1 = red4_add(s1); s2 = red4_add(s2);
    float mu = s1 * (1.f/180.f);
    float rstd = rsqrtf(s2 * (1.f/180.f) - mu*mu + 1e-5f);
    #pragma unroll
    for (int gi = 0; gi < 12; gi++){
      int c = c0 + gi*4;
      if (c < 180){
        u64 m = *(const u64*)(u.hx + row*S64 + c);
        f32x4 g = *(const f32x4*)(g1 + c);
        f32x4 be = *(const f32x4*)(be1 + c);
        float v0 = (bf2f((ushort_t)(m    )) - mu)*rstd*g.x + be.x;
        float v1 = (bf2f((ushort_t)(m>>16)) - mu)*rstd*g.y + be.y;
        float v2 = (bf2f((ushort_t)(m>>32)) - mu)*rstd*g.z + be.z;
        float v3 = (bf2f((ushort_t)(m>>48)) - mu)*rstd*g.w + be.w;
        *(u64*)(hn + row*S64 + c) = pack4(v0, v1, v2, v3);
      } else {
        *(u64*)(hn + row*S64 + c) = 0ull;
      }
    }
  }
  __syncthreads();

  // ---- attention: wave -> batch (wave>>1), head group (wave&1)*3 + hh
  {
    int bb = wave >> 1;
    ushort_t* buf0 = u.sc[wave][0];   // q, then vT
    ushort_t* buf1 = u.sc[wave][1];   // k, then P
    const float scl = 0.18257418583505537f;  // 30^-0.5

    for (int hh = 0; hh < 3; hh++){
      int head = (wave & 1)*3 + hh;
      const ushort_t* wbase = wqkv + head*96*192;

      // preload wq/wk A-frags (rows d): [mt][kk]
      short8 aqw[2][6], akw[2][6];
      #pragma unroll
      for (int mt = 0; mt < 2; mt++)
        #pragma unroll
        for (int kk = 0; kk < 6; kk++){
          aqw[mt][kk] = *(const short8*)(wbase + (      mt*16 + c16)*192 + kk*32 + quad*8);
          akw[mt][kk] = *(const short8*)(wbase + (32  + mt*16 + c16)*192 + kk*32 + quad*8);
        }

      f32x4 accq[2][2], acck[2][2], accv[2][2];
      #pragma unroll
      for (int i = 0; i < 2; i++)
        #pragma unroll
        for (int j = 0; j < 2; j++){ accq[i][j]=(f32x4)0.f; acck[i][j]=(f32x4)0.f; accv[i][j]=(f32x4)0.f; }

      #pragma unroll
      for (int kk = 0; kk < 6; kk++){
        short8 hf[2];
        #pragma unroll
        for (int nt = 0; nt < 2; nt++)
          hf[nt] = *(const short8*)(hn + (bb*32 + nt*16 + c16)*S64 + kk*32 + quad*8);
        short8 avw[2];
        #pragma unroll
        for (int nt = 0; nt < 2; nt++)
          avw[nt] = *(const short8*)(wbase + (64 + nt*16 + c16)*192 + kk*32 + quad*8);
        #pragma unroll
        for (int mt = 0; mt < 2; mt++)
          #pragma unroll
          for (int nt = 0; nt < 2; nt++){
            accq[mt][nt] = MFMA16(aqw[mt][kk], hf[nt], accq[mt][nt]);  // C[d][t] = qT
            acck[mt][nt] = MFMA16(akw[mt][kk], hf[nt], acck[mt][nt]);  // C[d][t] = kT
            accv[mt][nt] = MFMA16(hf[mt], avw[nt], accv[mt][nt]);      // C[t][d] = v
          }
      }
      // store q,k ROWMAJOR [t][d] via packed u64 (C rows = d contiguous per lane)
      #pragma unroll
      for (int mt = 0; mt < 2; mt++)
        #pragma unroll
        for (int nt = 0; nt < 2; nt++){
          *(u64*)(buf0 + (nt*16 + c16)*SSC + mt*16 + quad*4) =
            pack4(accq[mt][nt][0], accq[mt][nt][1], accq[mt][nt][2], accq[mt][nt][3]);
          *(u64*)(buf1 + (nt*16 + c16)*SSC + mt*16 + quad*4) =
            pack4(acck[mt][nt][0], acck[mt][nt][1], acck[mt][nt][2], acck[mt][nt][3]);
        }
      // S^T = MFMA(A=k, B=q): C[s][t]
      f32x4 sacc[2][2];
      #pragma unroll
      for (int i = 0; i < 2; i++){ sacc[i][0]=(f32x4)0.f; sacc[i][1]=(f32x4)0.f; }
      short8 ak[2], bq[2];
      #pragma unroll
      for (int mt = 0; mt < 2; mt++) ak[mt] = *(const short8*)(buf1 + (mt*16 + c16)*SSC + quad*8);
      #pragma unroll
      for (int nt = 0; nt < 2; nt++) bq[nt] = *(const short8*)(buf0 + (nt*16 + c16)*SSC + quad*8);
      #pragma unroll
      for (int mt = 0; mt < 2; mt++)
        #pragma unroll
        for (int nt = 0; nt < 2; nt++)
          sacc[mt][nt] = MFMA16(ak[mt], bq[nt], sacc[mt][nt]);
      // softmax: lane owns token t=nt*16+c16, 8 s-values in-lane; reduce over quads (xor16,32)
      #pragma unroll
      for (int nt = 0; nt < 2; nt++){
        int t = nt*16 + c16;
        float v[8];
        #pragma unroll
        for (int r = 0; r < 4; r++){
          int s0 = quad*4 + r, s1v = 16 + quad*4 + r;
          v[r]   = (s0  > t) ? -1e30f : sacc[0][nt][r]*scl;
          v[4+r] = (s1v > t) ? -1e30f : sacc[1][nt][r]*scl;
        }
        float m = v[0];
        #pragma unroll
        for (int i = 1; i < 8; i++) m = fmaxf(m, v[i]);
        m = fmaxf(m, __shfl_xor(m, 16));
        m = fmaxf(m, __shfl_xor(m, 32));
        float e[8], s = 0.f;
        #pragma unroll
        for (int i = 0; i < 8; i++){ e[i] = __expf(v[i] - m); s += e[i]; }
        s += __shfl_xor(s, 16);
        s += __shfl_xor(s, 32);
        float inv = 1.f / s;
        // P rowmajor [t][s] packed (overwrites k in buf1; k already consumed)
        *(u64*)(buf1 + t*SSC +      quad*4) = pack4(e[0]*inv, e[1]*inv, e[2]*inv, e[3]*inv);
        *(u64*)(buf1 + t*SSC + 16 + quad*4) = pack4(e[4]*inv, e[5]*inv, e[6]*inv, e[7]*inv);
      }
      // vT [d][t] packed into buf0 (q consumed)
      #pragma unroll
      for (int mt = 0; mt < 2; mt++)
        #pragma unroll
        for (int nt = 0; nt < 2; nt++)
          *(u64*)(buf0 + (nt*16 + c16)*SSC + mt*16 + quad*4) =
            pack4(accv[mt][nt][0], accv[mt][nt][1], accv[mt][nt][2], accv[mt][nt][3]);
      // PV: C[d][t] = MFMA(A=vT, B=P)
      f32x4 oacc[2][2];
      #pragma unroll
      for (int i = 0; i < 2; i++){ oacc[i][0]=(f32x4)0.f; oacc[i][1]=(f32x4)0.f; }
      short8 av[2], bp[2];
      #pragma unroll
      for (int mt = 0; mt < 2; mt++) av[mt] = *(const short8*)(buf0 + (mt*16 + c16)*SSC + quad*8);
      #pragma unroll
      for (int nt = 0; nt < 2; nt++) bp[nt] = *(const short8*)(buf1 + (nt*16 + c16)*SSC + quad*8);
      #pragma unroll
      for (int mt = 0; mt < 2; mt++)
        #pragma unroll
        for (int nt = 0; nt < 2; nt++)
          oacc[mt][nt] = MFMA16(av[mt], bp[nt], oacc[mt][nt]);
      // att[token][head*32+d] packed (d contiguous per lane)
      #pragma unroll
      for (int mt = 0; mt < 2; mt++)
        #pragma unroll
        for (int nt = 0; nt < 2; nt++)
          *(u64*)(att + (bb*32 + nt*16 + c16)*S64 + head*32 + mt*16 + quad*4) =
            pack4(oacc[mt][nt][0], oacc[mt][nt][1], oacc[mt][nt][2], oacc[mt][nt][3]);
    }
  }
  __syncthreads();

  // x2 = x (fp32 re-read, L2-hot) + attn ; coalesced f32x4 store
  #pragma unroll
  for (int it = 0; it < 12; it++){
    int idx = it*256 + tid;
    if (idx < 2880){
      f32x4 v = *(const f32x4*)(x + base + (long)idx*4);
      int row = (int)(((u32)idx * 745655u) >> 25);
      int col4 = (idx - row*45)*4;
      #pragma unroll
      for (int e = 0; e < 4; e++){
        int c = col4 + e;
        int h = (c*4370) >> 17;     // c/30
        int d = c - h*30;
        v[e] += bf2f(att[row*S64 + h*32 + d]);
      }
      *(f32x4*)(xout + base + (long)idx*4) = v;
    }
  }
}

union MlpU { ushort_t hx[64*S64]; };   // x2 bf16 -> act chunk -> mlp out

// ---------------- Kernel 2: LN2 + MLP ; in-place residual update of d_out
// 256 thr = 4 waves ; 64 tokens/block
__global__ __launch_bounds__(256, 2)
void mlp_kernel(const float* __restrict__ g2, const float* __restrict__ be2,
                const float* __restrict__ b1, const float* __restrict__ b2,
                const ushort_t* __restrict__ w1t, const ushort_t* __restrict__ w2t,
                float* __restrict__ xio){
  __shared__ MlpU u;                 // x2 bf16, then act chunk, then mlp out
  __shared__ ushort_t hn[64*S64];    // LN2 out (cols 180..191 zero)
  int tid = threadIdx.x;
  int wave = tid >> 6, lane = tid & 63;
  int quad = lane >> 4, c16 = lane & 15;
  long base = (long)blockIdx.x * 11520;

  // Phase A: x2 -> hx bf16
  #pragma unroll
  for (int it = 0; it < 12; it++){
    int idx = it*256 + tid;
    if (idx < 2880){
      f32x4 v = *(const f32x4*)(xio + base + (long)idx*4);
      int row = (int)(((u32)idx * 745655u) >> 25);
      int col = idx - row*45;
      *(u64*)(u.hx + row*S64 + col*4) = pack4(v.x, v.y, v.z, v.w);
    } else {
      int p = idx - 2880;
      int row = (p*21846) >> 16;
      int g = p - row*3;
      *(u64*)(u.hx + row*S64 + 180 + g*4) = 0ull;
    }
  }
  __syncthreads();

  // LN2
  {
    int row = tid >> 2, sub = tid & 3;
    int c0 = sub*48;
    float s1 = 0.f, s2 = 0.f;
    #pragma unroll
    for (int gi = 0; gi < 12; gi++){
      u64 m = *(const u64*)(u.hx + row*S64 + c0 + gi*4);
      #pragma unroll
      for (int e = 0; e < 4; e++){
        float v = bf2f((ushort_t)(m >> (16*e)));
        s1 += v; s2 += v*v;
      }
    }
    s1 = red4_add(s1); s2 = red4_add(s2);
    float mu = s1 * (1.f/180.f);
    float rstd = rsqrtf(s2 * (1.f/180.f) - mu*mu + 1e-5f);
    #pragma unroll
    for (int gi = 0; gi < 12; gi++){
      int c = c0 + gi*4;
      if (c < 180){
        u64 m = *(const u64*)(u.hx + row*S64 + c);
        f32x4 g = *(const f32x4*)(g2 + c);
        f32x4 be = *(const f32x4*)(be2 + c);
        float v0 = (bf2f((ushort_t)(m    )) - mu)*rstd*g.x + be.x;
        float v1 = (bf2f((ushort_t)(m>>16)) - mu)*rstd*g.y + be.y;
        float v2 = (bf2f((ushort_t)(m>>32)) - mu)*rstd*g.z + be.z;
        float v3 = (bf2f((ushort_t)(m>>48)) - mu)*rstd*g.w + be.w;
        *(u64*)(hn + row*S64 + c) = pack4(v0, v1, v2, v3);
      } else {
        *(u64*)(hn + row*S64 + c) = 0ull;
      }
    }
  }
  __syncthreads();

  ushort_t* act = u.hx;   // x2 copy dead after LN2
  f32x4 outacc[3][4];     // C[no][t]: wave owns 48 no x 64 t
  #pragma unroll
  for (int i = 0; i < 3; i++)
    #pragma unroll
    for (int j = 0; j < 4; j++) outacc[i][j] = (f32x4)0.f;

  for (int ch = 0; ch < 4; ch++){
    // preload w1 A-frags for this chunk: rows n (48/wave), [mi][kk]
    short8 aw[3][6];
    #pragma unroll
    for (int mi = 0; mi < 3; mi++)
      #pragma unroll
      for (int kk = 0; kk < 6; kk++)
        aw[mi][kk] = *(const short8*)(w1t + (size_t)(ch*192 + (wave*3+mi)*16 + c16)*192 + kk*32 + quad*8);

    // MLP1: C[n][t] = MFMA(A=w1 rows n, B=hn rows t)
    f32x4 aacc[3][4];
    #pragma unroll
    for (int i = 0; i < 3; i++)
      #pragma unroll
      for (int j = 0; j < 4; j++) aacc[i][j] = (f32x4)0.f;
    #pragma unroll
    for (int kk = 0; kk < 6; kk++){
      short8 bh[4];
      #pragma unroll
      for (int tt = 0; tt < 4; tt++)
        bh[tt] = *(const short8*)(hn + (tt*16 + c16)*S64 + kk*32 + quad*8);
      #pragma unroll
      for (int mi = 0; mi < 3; mi++)
        #pragma unroll
        for (int tt = 0; tt < 4; tt++)
          aacc[mi][tt] = MFMA16(aw[mi][kk], bh[tt], aacc[mi][tt]);
    }
    __syncthreads();   // prev chunk's MLP2 done reading act
    // bias + relu + packed store act[t][n] (n contiguous per lane)
    #pragma unroll
    for (int mi = 0; mi < 3; mi++){
      int nrel = (wave*3+mi)*16 + quad*4;
      int nabs = ch*192 + nrel;
      f32x4 bias = (f32x4)0.f;
      if (nabs < 720) bias = *(const f32x4*)(b1 + nabs);
      #pragma unroll
      for (int tt = 0; tt < 4; tt++){
        float v0 = fmaxf(aacc[mi][tt][0] + bias[0], 0.f);
        float v1 = fmaxf(aacc[mi][tt][1] + bias[1], 0.f);
        float v2 = fmaxf(aacc[mi][tt][2] + bias[2], 0.f);
        float v3 = fmaxf(aacc[mi][tt][3] + bias[3], 0.f);
        *(u64*)(act + (tt*16 + c16)*S64 + nrel) = pack4(v0, v1, v2, v3);
      }
    }
    __syncthreads();   // act ready

    // preload w2 A-frags: rows no (48/wave), [ntl][kk]
    short8 bw[3][6];
    #pragma unroll
    for (int ntl = 0; ntl < 3; ntl++)
      #pragma unroll
      for (int kk = 0; kk < 6; kk++)
        bw[ntl][kk] = *(const short8*)(w2t + (size_t)(wave*48 + ntl*16 + c16)*768 + ch*192 + kk*32 + quad*8);

    // MLP2: C[no][t] += MFMA(A=w2 rows no, B=act rows t)
    #pragma unroll
    for (int kk = 0; kk < 6; kk++){
      short8 aa[4];
      #pragma unroll
      for (int tt = 0; tt < 4; tt++)
        aa[tt] = *(const short8*)(act + (tt*16 + c16)*S64 + kk*32 + quad*8);
      #pragma unroll
      for (int ntl = 0; ntl < 3; ntl++)
        #pragma unroll
        for (int tt = 0; tt < 4; tt++)
          outacc[ntl][tt] = MFMA16(bw[ntl][kk], aa[tt], outacc[ntl][tt]);
    }
  }
  __syncthreads();   // all waves done reading act (last chunk)
  // mlp out bf16 -> act buffer [t][no] (no contiguous per lane)
  #pragma unroll
  for (int ntl = 0; ntl < 3; ntl++){
    int no = wave*48 + ntl*16 + quad*4;
    #pragma unroll
    for (int tt = 0; tt < 4; tt++)
      *(u64*)(act + (tt*16 + c16)*S64 + no) =
        pack4(outacc[ntl][tt][0], outacc[ntl][tt][1], outacc[ntl][tt][2], outacc[ntl][tt][3]);
  }
  __syncthreads();
  // out = x2 + mlp + b2 ; coalesced f32x4
  #pragma unroll
  for (int it = 0; it < 12; it++){
    int idx = it*256 + tid;
    if (idx < 2880){
      f32x4 v = *(const f32x4*)(xio + base + (long)idx*4);
      int row = (int)(((u32)idx * 745655u) >> 25);
      int col4 = (idx - row*45)*4;
      f32x4 bb = *(const f32x4*)(b2 + col4);
      u64 m = *(const u64*)(act + row*S64 + col4);
      v.x += bf2f((ushort_t)(m      )) + bb.x;
      v.y += bf2f((ushort_t)(m >> 16)) + bb.y;
      v.z += bf2f((ushort_t)(m >> 32)) + bb.z;
      v.w += bf2f((ushort_t)(m >> 48)) + bb.w;
      *(f32x4*)(xio + base + (long)idx*4) = v;
    }
  }
}

extern "C" void kernel_launch(void* const* d_in, const int* in_sizes, int n_in,
                              void* d_out, int out_size, void* d_ws, size_t ws_size,
                              hipStream_t stream) {
  const float* x   = (const float*)d_in[0];
  const float* wq  = (const float*)d_in[1];
  const float* wk  = (const float*)d_in[2];
  const float* wv  = (const float*)d_in[3];
  const float* g1  = (const float*)d_in[4];
  const float* be1 = (const float*)d_in[5];
  const float* g2  = (const float*)d_in[6];
  const float* be2 = (const float*)d_in[7];
  const float* w1  = (const float*)d_in[8];
  const float* b1  = (const float*)d_in[9];
  const float* w2  = (const float*)d_in[10];
  const float* b2  = (const float*)d_in[11];
  ushort_t* ws   = (ushort_t*)d_ws;
  ushort_t* wqkv = ws;
  ushort_t* w1t  = ws + WQKV_ELEMS;
  ushort_t* w2t  = w1t + W1T_ELEMS;
  float* out = (float*)d_out;

  prep_weights<<<256, 256, 0, stream>>>(wq, wk, wv, w1, w2, ws);
  attn_kernel<<<2048, 256, 0, stream>>>(x, g1, be1, wqkv, out);
  mlp_kernel<<<2048, 256, 0, stream>>>(g2, be2, b1, b2, w1t, w2t, out);
}